// Round 3
// baseline (614.096 us; speedup 1.0000x reference)
//
#include <hip/hip_runtime.h>
#include <hip/hip_bf16.h>
#include <stdint.h>

typedef __bf16 bf16_t;
typedef __bf16 bf16x4 __attribute__((ext_vector_type(4)));
typedef __bf16 bf16x8 __attribute__((ext_vector_type(8)));
typedef float floatx4 __attribute__((ext_vector_type(4)));

#define B_ 32
#define HP 58
#define WP 66

// ws layout (bytes)
#define XPAD_OFF   0u
#define WAGG_OFF   62717952u     // 32*58*66*256*2
#define POOLED_OFF 100466688u    // + 32*9*256*256*2
#define ATTN_OFF   100499456u
#define BIASAGG_OFF 100499968u   // first 8KB doubles as hs[] before biasagg is written

__device__ __forceinline__ void async_copy16(const void* gsrc, void* ldst) {
  __builtin_amdgcn_global_load_lds(
      (const __attribute__((address_space(1))) unsigned int*)gsrc,
      (__attribute__((address_space(3))) unsigned int*)ldst, 16, 0, 0);
}

// ---------------- kernel 1: pad + convert + GAP partial sums ----------------
// v3: float4 loads, bf16x4 stores, 4 w-quarters per block, LDS-reduced GAP.
__global__ __launch_bounds__(256)
void pad_pool(const float* __restrict__ x, bf16_t* __restrict__ xpad,
              float* __restrict__ pooled) {
  const int hp = blockIdx.x;   // 0..57
  const int b  = blockIdx.y;
  const int t  = threadIdx.x;
  const int wq = t >> 6, cl = t & 63, c0 = cl * 4;
  const int h  = hp - 1;
  const bool hvalid = (h >= 0) && (h < 56);
  bf16_t* dst = xpad + ((size_t)(b * 58 + hp)) * (66 * 256);
  const float* srow = x + ((size_t)(b * 56 + (hvalid ? h : 0))) * (56 * 256);
  floatx4 s = {0.f, 0.f, 0.f, 0.f};
  const int wp0 = wq * 17;
  const int wpend = (wp0 + 17 < 66) ? wp0 + 17 : 66;
  for (int wp = wp0; wp < wpend; ++wp) {
    int w = wp - 1;
    floatx4 v = {0.f, 0.f, 0.f, 0.f};
    if (hvalid && (unsigned)w < 56u) {
      v = *(const floatx4*)(srow + w * 256 + c0);
      s += v;
    }
    bf16x4 r = {(bf16_t)v.x, (bf16_t)v.y, (bf16_t)v.z, (bf16_t)v.w};
    *(bf16x4*)(dst + wp * 256 + c0) = r;
  }
  __shared__ floatx4 red4[4][64];
  red4[wq][cl] = s;
  __syncthreads();
  if (wq == 0 && hvalid) {
    floatx4 tot = red4[0][cl] + red4[1][cl] + red4[2][cl] + red4[3][cl];
    atomicAdd(&pooled[b * 256 + c0 + 0], tot.x);
    atomicAdd(&pooled[b * 256 + c0 + 1], tot.y);
    atomicAdd(&pooled[b * 256 + c0 + 2], tot.z);
    atomicAdd(&pooled[b * 256 + c0 + 3], tot.w);
  }
}

// ---------------- kernel 2a: hidden layer (8 blocks) ----------------
__global__ __launch_bounds__(256)
void router_hidden(const float* __restrict__ pooled, const float* __restrict__ w1,
                   const float* __restrict__ b1, float* __restrict__ hs) {
  const int idx = blockIdx.x * 256 + threadIdx.x;  // 0..2047
  const int b = idx >> 6, j = idx & 63;            // b wave-uniform
  float s = b1[j];
  const float* pb = pooled + b * 256;
#pragma unroll 8
  for (int c = 0; c < 256; ++c)
    s = fmaf(pb[c] * (1.0f / 3136.0f), w1[c * 64 + j], s);
  hs[idx] = fmaxf(s, 0.f);
}

// ---------------- kernel 2b: logits + softmax + bias agg (1 block) ----------------
__global__ __launch_bounds__(256)
void router_tail(const float* __restrict__ hs, const float* __restrict__ w2,
                 const float* __restrict__ b2, const float* __restrict__ biases,
                 float* __restrict__ attn, float* __restrict__ biasagg) {
  __shared__ float lg[128];
  __shared__ float at[128];
  const int t = threadIdx.x;
  if (t < 128) {
    int b = t >> 2, k = t & 3;
    float s = b2[k];
    const float* hb = hs + b * 64;
    for (int j = 0; j < 64; ++j) s += hb[j] * w2[j * 4 + k];
    lg[t] = s * (1.0f / 30.0f);
  }
  __syncthreads();
  if (t < 32) {
    int b = t;
    float z0 = lg[b*4], z1 = lg[b*4+1], z2 = lg[b*4+2], z3 = lg[b*4+3];
    float m = fmaxf(fmaxf(z0, z1), fmaxf(z2, z3));
    float e0 = expf(z0-m), e1 = expf(z1-m), e2 = expf(z2-m), e3 = expf(z3-m);
    float inv = 1.0f / (e0 + e1 + e2 + e3);
    at[b*4] = e0*inv; at[b*4+1] = e1*inv; at[b*4+2] = e2*inv; at[b*4+3] = e3*inv;
    attn[b*4] = at[b*4]; attn[b*4+1] = at[b*4+1];
    attn[b*4+2] = at[b*4+2]; attn[b*4+3] = at[b*4+3];
  }
  __syncthreads();   // all hs reads done before biasagg overwrites the region
  for (int i = t; i < 8192; i += 256) {
    int b = i >> 8, f = i & 255;
    biasagg[i] = at[b*4]*biases[f] + at[b*4+1]*biases[256+f]
               + at[b*4+2]*biases[512+f] + at[b*4+3]*biases[768+f];
  }
}

// ---------------- kernel 3: weight aggregation + transpose to [b][tap][f][c] ----------------
__global__ __launch_bounds__(256)
void wagg_kernel(const float* __restrict__ kers, const float* __restrict__ attn,
                 bf16_t* __restrict__ wagg) {
  const int cq  = blockIdx.x;  // 0..3  (c quarter)
  const int tap = blockIdx.y;  // 0..8
  const int b   = blockIdx.z;  // 0..31
  const int t   = threadIdx.x;
  __shared__ bf16_t tile[64 * 260];

  const float a0 = attn[b*4+0], a1 = attn[b*4+1], a2 = attn[b*4+2], a3 = attn[b*4+3];
  const float* k0 = kers + ((size_t)(0 * 9 + tap)) * 65536;
  const float* k1 = kers + ((size_t)(1 * 9 + tap)) * 65536;
  const float* k2 = kers + ((size_t)(2 * 9 + tap)) * 65536;
  const float* k3 = kers + ((size_t)(3 * 9 + tap)) * 65536;

  const int fq = t & 63;
  const int cl = t >> 6;
  const int f0 = fq * 4;
#pragma unroll
  for (int pass = 0; pass < 16; ++pass) {
    const int c_local = pass * 4 + cl;
    const size_t o = (size_t)(cq * 64 + c_local) * 256 + f0;
    floatx4 v0 = *(const floatx4*)(k0 + o);
    floatx4 v1 = *(const floatx4*)(k1 + o);
    floatx4 v2 = *(const floatx4*)(k2 + o);
    floatx4 v3 = *(const floatx4*)(k3 + o);
    bf16x4 r;
#pragma unroll
    for (int j = 0; j < 4; ++j)
      r[j] = (bf16_t)(a0 * v0[j] + a1 * v1[j] + a2 * v2[j] + a3 * v3[j]);
    *(bf16x4*)&tile[c_local * 260 + f0] = r;
  }
  __syncthreads();

  bf16_t* wt = wagg + ((size_t)(b * 9 + tap)) * 65536 + cq * 64;
#pragma unroll
  for (int pass = 0; pass < 8; ++pass) {
    const int gi = pass * 256 + t;
    const int f  = gi >> 3;
    const int cg = gi & 7;
    bf16x8 v;
#pragma unroll
    for (int i = 0; i < 8; ++i) v[i] = tile[(cg * 8 + i) * 260 + f];
    *(bf16x8*)(wt + (size_t)f * 256 + cg * 8) = v;
  }
}

// ---------------- kernel 4: implicit-GEMM conv ----------------
// v3: B loaded global->VGPR (reg double-buffer, no LDS, no reuse to exploit);
// A patch LDS double-buffered per c-quarter; __syncthreads only at cq swap (4/block).
// XCD-aware 1D grid: each b's 28 tiles + wagg[b] pinned to one XCD's L2.
#define PBUF_BYTES 20480   // 160 pos * 8 granules * 16B

__global__ __launch_bounds__(256, 2)
void conv_mfma(const bf16_t* __restrict__ xpad, const bf16_t* __restrict__ wagg,
               const float* __restrict__ biasagg, float* __restrict__ out) {
  __shared__ char ldsP[2 * PBUF_BYTES];  // 40960 B

  const int id   = blockIdx.x;          // 0..895
  const int b    = (id & 7) * 4 + ((id >> 3) / 28);
  const int tile = (id >> 3) % 28;
  const int h0 = (tile >> 2) * 8;
  const int w0 = (tile & 3) * 14;

  const int tid  = threadIdx.x;
  const int lane = tid & 63;
  const int wv   = tid >> 6;
  const int l15  = lane & 15;
  const int quad = lane >> 4;
  const int n0   = wv * 64;

  const char* xb = (const char*)xpad + (size_t)b * (HP * WP * 256 * 2);
  const char* wb = (const char*)wagg + (size_t)b * (9 * 256 * 256 * 2);
  const int laneB = (n0 + l15) * 512 + quad * 16;

  int offs[7];
#pragma unroll
  for (int mi = 0; mi < 7; ++mi) {
    int m = mi * 16 + l15;
    int ty = m / 14;
    int tx = m - ty * 14;
    offs[mi] = ty * 16 + tx;
  }

  floatx4 acc[7][4];
#pragma unroll
  for (int mi = 0; mi < 7; ++mi)
#pragma unroll
    for (int ni = 0; ni < 4; ++ni) acc[mi][ni] = (floatx4){0.f, 0.f, 0.f, 0.f};

  auto stage_patch = [&](int cq, int pb) {
#pragma unroll
    for (int ii = 0; ii < 5; ++ii) {
      int i20 = wv * 5 + ii;            // wave-uniform
      int p = i20 * 8 + (lane >> 3);    // patch position 0..159
      int gsrc = (lane & 7) ^ (p & 7);  // XOR swizzle
      const char* src = xb + ((size_t)((h0 + (p >> 4)) * WP + (w0 + (p & 15))) * 512)
                           + cq * 128 + gsrc * 16;
      async_copy16(src, ldsP + pb * PBUF_BYTES + i20 * 1024);
    }
  };
  auto load_b4 = [&](bf16x8* dst, int cq, int tap, int ks) {
    const char* base = wb + (size_t)tap * 131072 + cq * 128 + ks * 64 + laneB;
#pragma unroll
    for (int ni = 0; ni < 4; ++ni)
      dst[ni] = *(const bf16x8*)(base + ni * 8192);
  };

  bf16x8 bcur[4], bnxt[4];
  stage_patch(0, 0);
  load_b4(bcur, 0, 0, 0);
  __syncthreads();

  for (int cq = 0; cq < 4; ++cq) {
    const char* pc = ldsP + (cq & 1) * PBUF_BYTES;
    for (int tap = 0; tap < 9; ++tap) {
      const int tapoff = (tap / 3) * 16 + (tap % 3);
#pragma unroll
      for (int ks = 0; ks < 2; ++ks) {
        const bool last = (tap == 8) && (ks == 1);
        if (!last) {
          load_b4(bnxt, cq, tap + ks, ks ^ 1);
        } else if (cq < 3) {
          stage_patch(cq + 1, (cq + 1) & 1);
          load_b4(bnxt, cq + 1, 0, 0);
        }
        const int gA = ks * 4 + quad;
        bf16x8 a[7];
#pragma unroll
        for (int mi = 0; mi < 7; ++mi) {
          int p = offs[mi] + tapoff;
          a[mi] = *(const bf16x8*)(pc + (p << 7) + ((gA ^ (p & 7)) << 4));
        }
#pragma unroll
        for (int mi = 0; mi < 7; ++mi)
#pragma unroll
          for (int ni = 0; ni < 4; ++ni)
            acc[mi][ni] = __builtin_amdgcn_mfma_f32_16x16x32_bf16(a[mi], bcur[ni], acc[mi][ni], 0, 0, 0);
#pragma unroll
        for (int ni = 0; ni < 4; ++ni) bcur[ni] = bnxt[ni];
      }
    }
    if (cq < 3) __syncthreads();
  }

  // epilogue: D layout col=lane&15 (f), row=quad*4+reg (m)
  float bias[4];
#pragma unroll
  for (int ni = 0; ni < 4; ++ni) bias[ni] = biasagg[b * 256 + n0 + ni * 16 + l15];
  float* outb = out + (size_t)b * (56 * 56 * 256);
#pragma unroll
  for (int mi = 0; mi < 7; ++mi) {
#pragma unroll
    for (int rg = 0; rg < 4; ++rg) {
      int m = mi * 16 + quad * 4 + rg;
      int ty = m / 14, tx = m - ty * 14;
      float* orow = outb + ((size_t)((h0 + ty) * 56) + (w0 + tx)) * 256 + n0 + l15;
#pragma unroll
      for (int ni = 0; ni < 4; ++ni) orow[ni * 16] = acc[mi][ni][rg] + bias[ni];
    }
  }
}

extern "C" void kernel_launch(void* const* d_in, const int* in_sizes, int n_in,
                              void* d_out, int out_size, void* d_ws, size_t ws_size,
                              hipStream_t stream) {
  const float* x      = (const float*)d_in[0];
  const float* kers   = (const float*)d_in[1];
  const float* biases = (const float*)d_in[2];
  const float* w1     = (const float*)d_in[3];
  const float* b1     = (const float*)d_in[4];
  const float* w2     = (const float*)d_in[5];
  const float* b2     = (const float*)d_in[6];
  float* outp = (float*)d_out;
  char* ws = (char*)d_ws;

  bf16_t* xpad   = (bf16_t*)(ws + XPAD_OFF);
  bf16_t* wagg   = (bf16_t*)(ws + WAGG_OFF);
  float* pooled  = (float*)(ws + POOLED_OFF);
  float* attn    = (float*)(ws + ATTN_OFF);
  float* biasagg = (float*)(ws + BIASAGG_OFF);
  float* hs      = (float*)(ws + BIASAGG_OFF);  // aliased; router_tail orders read->write

  hipMemsetAsync(pooled, 0, 32 * 256 * sizeof(float), stream);
  pad_pool<<<dim3(58, 32), 256, 0, stream>>>(x, xpad, pooled);
  router_hidden<<<8, 256, 0, stream>>>(pooled, w1, b1, hs);
  router_tail<<<1, 256, 0, stream>>>(hs, w2, b2, biases, attn, biasagg);
  wagg_kernel<<<dim3(4, 9, 32), 256, 0, stream>>>(kers, attn, wagg);
  conv_mfma<<<896, 256, 0, stream>>>(xpad, wagg, biasagg, outp);
}